// Round 8
// baseline (221.264 us; speedup 1.0000x reference)
//
#include <hip/hip_runtime.h>

// Paged KV-cache scatter write (float32).
//   kv_pages: (4096, 16, 16, 128)  -> out (full copy + scatter)
//   new_k, new_v: (8192, 8, 128)
//   t_pages, t_slots: (8192,) int32
// Semantics: out[p,s,0::2,:] = new_k[i]; out[p,s,1::2,:] = new_v[i]
// with numpy last-write-wins on duplicate (p,s) and mode='drop' bounds.
//
// R8: SINGLE fused kernel. The 3-dispatch (memset -> atomicMax winners ->
// write) structure failed post-timing validation once (stale winner across
// graph replays — cross-XCD L2 visibility of the workspace handoff is the
// suspect). This version has no workspace and no cross-dispatch edges:
// each block scans the 64 KB token index arrays (L2-resident) and resolves
// winners for its 8 rows in LDS via atomicMax + __syncthreads — deterministic
// (max is order-independent), self-contained, same every call.
// Streaming path = R3's best recipe: 8 rows/block, nt loads + nt stores.

#define NUM_PAGES 4096
#define PAGE_SIZE 16
#define KV_HEADS 8
#define HEAD_SIZE 128
#define N_TOKENS 8192
#define NUM_ROWS (NUM_PAGES * PAGE_SIZE)       // 65536 (page,slot) rows
#define ROW_F4 (2 * KV_HEADS * HEAD_SIZE / 4)  // 512 f32x4 per row (8 KiB)
#define ROWS_PER_BLOCK 8                       // 64 KiB streamed per block

typedef float f32x4 __attribute__((ext_vector_type(4)));

__global__ __launch_bounds__(256)
void kv_fused_kernel(const f32x4* __restrict__ kv_pages,
                     const float* __restrict__ new_k,
                     const float* __restrict__ new_v,
                     const int* __restrict__ t_pages,
                     const int* __restrict__ t_slots,
                     f32x4* __restrict__ out) {
    __shared__ int wlds[ROWS_PER_BLOCK];
    const int row0 = blockIdx.x * ROWS_PER_BLOCK;
    const int tid  = threadIdx.x;

    if (tid < ROWS_PER_BLOCK) wlds[tid] = -1;
    __syncthreads();

    // Winner scan: all 8192 tokens (plain cached loads — L2-resident, 64 KB
    // total). A token claims a row in [row0, row0+8) via LDS atomicMax so the
    // largest token index (numpy last-write-wins) survives.
    #pragma unroll 4
    for (int i = tid; i < N_TOKENS; i += 256) {
        int p = t_pages[i];
        int s = t_slots[i];
        // mode='drop': out-of-range indices are ignored
        if ((unsigned)p < (unsigned)NUM_PAGES && (unsigned)s < (unsigned)PAGE_SIZE) {
            int d = p * PAGE_SIZE + s - row0;
            if ((unsigned)d < (unsigned)ROWS_PER_BLOCK)
                atomicMax(&wlds[d], i);
        }
    }
    __syncthreads();

    // Streaming pass: copy untouched rows, scatter overwritten rows.
    #pragma unroll
    for (int r = 0; r < ROWS_PER_BLOCK; ++r) {
        const int w = wlds[r];                    // block-uniform (broadcast)
        const size_t base4 = (size_t)(row0 + r) * ROW_F4;
        if (w < 0) {
            // untouched row: streaming copy (nt load + nt store)
            #pragma unroll
            for (int t = tid; t < ROW_F4; t += 256) {
                f32x4 v = __builtin_nontemporal_load(&kv_pages[base4 + t]);
                __builtin_nontemporal_store(v, &out[base4 + t]);
            }
        } else {
            // overwritten row: interleave new_k (even heads) / new_v (odd heads)
            #pragma unroll
            for (int t = tid; t < ROW_F4; t += 256) {
                int head = t >> 5;                       // 32 f32x4 per head
                int d4   = t & 31;
                const float* src = (head & 1) ? new_v : new_k;
                size_t off = ((size_t)w * KV_HEADS + (head >> 1)) * HEAD_SIZE + d4 * 4;
                f32x4 v = __builtin_nontemporal_load(
                    reinterpret_cast<const f32x4*>(src + off));
                __builtin_nontemporal_store(v, &out[base4 + t]);
            }
        }
    }
}

extern "C" void kernel_launch(void* const* d_in, const int* in_sizes, int n_in,
                              void* d_out, int out_size, void* d_ws, size_t ws_size,
                              hipStream_t stream) {
    const float* kv_pages = (const float*)d_in[0];
    const float* new_k    = (const float*)d_in[1];
    const float* new_v    = (const float*)d_in[2];
    const int*   t_pages  = (const int*)d_in[3];
    const int*   t_slots  = (const int*)d_in[4];
    float*       out      = (float*)d_out;

    kv_fused_kernel<<<NUM_ROWS / ROWS_PER_BLOCK, 256, 0, stream>>>(
        (const f32x4*)kv_pages, new_k, new_v, t_pages, t_slots, (f32x4*)out);
}

// Round 9
// 217.981 us; speedup vs baseline: 1.0151x; 1.0151x over previous
//
#include <hip/hip_runtime.h>

// Paged KV-cache scatter write (float32).
//   kv_pages: (4096, 16, 16, 128)  -> out (full copy + scatter)
//   new_k, new_v: (8192, 8, 128)
//   t_pages, t_slots: (8192,) int32
// Semantics: out[p,s,0::2,:] = new_k[i]; out[p,s,1::2,:] = new_v[i]
// with numpy last-write-wins on duplicate (p,s) and mode='drop' bounds.
//
// R9: single fused kernel (multi-dispatch handoff failed post-timing
// revalidation in R7 — stale-winner signature; fused is the only structure
// proven safe under graph replay). Each block resolves winners for its own
// rows by scanning the token arrays into an LDS atomicMax table, then streams.
// vs R8: ROWS_PER_BLOCK 8->32 (aggregate scan traffic 537->134 MB, scan is
// ~6% of block work instead of ~25%; grid 2048 = exactly full wave capacity)
// and int4-vectorized scan loads (8 iters instead of 32, deeper MLP).
// Streaming path: nt loads + nt stores (best known, R3/R8).

#define NUM_PAGES 4096
#define PAGE_SIZE 16
#define KV_HEADS 8
#define HEAD_SIZE 128
#define N_TOKENS 8192
#define NUM_ROWS (NUM_PAGES * PAGE_SIZE)       // 65536 (page,slot) rows
#define ROW_F4 (2 * KV_HEADS * HEAD_SIZE / 4)  // 512 f32x4 per row (8 KiB)
#define ROWS_PER_BLOCK 32                      // 256 KiB streamed per block, grid 2048

typedef float f32x4 __attribute__((ext_vector_type(4)));
typedef int   i32x4 __attribute__((ext_vector_type(4)));

__global__ __launch_bounds__(256)
void kv_fused_kernel(const f32x4* __restrict__ kv_pages,
                     const float* __restrict__ new_k,
                     const float* __restrict__ new_v,
                     const i32x4* __restrict__ t_pages4,
                     const i32x4* __restrict__ t_slots4,
                     f32x4* __restrict__ out) {
    __shared__ int wlds[ROWS_PER_BLOCK];
    const int row0 = blockIdx.x * ROWS_PER_BLOCK;
    const int tid  = threadIdx.x;

    if (tid < ROWS_PER_BLOCK) wlds[tid] = -1;
    __syncthreads();

    // Winner scan: all 8192 tokens, int4-vectorized (2048 vec elements, 8
    // iterations per thread). Token arrays are 64 KB total — L2/L3 resident.
    // Expected hits per block ~4, so the atomic path is cold.
    #pragma unroll
    for (int i = tid; i < N_TOKENS / 4; i += 256) {
        i32x4 p4 = t_pages4[i];
        i32x4 s4 = t_slots4[i];
        #pragma unroll
        for (int c = 0; c < 4; ++c) {
            int p = p4[c], s = s4[c];
            // mode='drop': out-of-range indices are ignored
            if ((unsigned)p < (unsigned)NUM_PAGES && (unsigned)s < (unsigned)PAGE_SIZE) {
                int d = p * PAGE_SIZE + s - row0;
                if ((unsigned)d < (unsigned)ROWS_PER_BLOCK)
                    atomicMax(&wlds[d], i * 4 + c);   // last token index wins
            }
        }
    }
    __syncthreads();

    // Streaming pass: copy untouched rows, scatter overwritten rows.
    for (int r = 0; r < ROWS_PER_BLOCK; ++r) {
        const int w = wlds[r];                    // block-uniform (broadcast)
        const size_t base4 = (size_t)(row0 + r) * ROW_F4;
        if (w < 0) {
            // untouched row: streaming copy (nt load + nt store)
            #pragma unroll
            for (int t = tid; t < ROW_F4; t += 256) {
                f32x4 v = __builtin_nontemporal_load(&kv_pages[base4 + t]);
                __builtin_nontemporal_store(v, &out[base4 + t]);
            }
        } else {
            // overwritten row: interleave new_k (even heads) / new_v (odd heads)
            #pragma unroll
            for (int t = tid; t < ROW_F4; t += 256) {
                int head = t >> 5;                       // 32 f32x4 per head
                int d4   = t & 31;
                const float* src = (head & 1) ? new_v : new_k;
                size_t off = ((size_t)w * KV_HEADS + (head >> 1)) * HEAD_SIZE + d4 * 4;
                f32x4 v = __builtin_nontemporal_load(
                    reinterpret_cast<const f32x4*>(src + off));
                __builtin_nontemporal_store(v, &out[base4 + t]);
            }
        }
    }
}

extern "C" void kernel_launch(void* const* d_in, const int* in_sizes, int n_in,
                              void* d_out, int out_size, void* d_ws, size_t ws_size,
                              hipStream_t stream) {
    const float* kv_pages = (const float*)d_in[0];
    const float* new_k    = (const float*)d_in[1];
    const float* new_v    = (const float*)d_in[2];
    const int*   t_pages  = (const int*)d_in[3];
    const int*   t_slots  = (const int*)d_in[4];
    float*       out      = (float*)d_out;

    kv_fused_kernel<<<NUM_ROWS / ROWS_PER_BLOCK, 256, 0, stream>>>(
        (const f32x4*)kv_pages, new_k, new_v,
        (const i32x4*)t_pages, (const i32x4*)t_slots, (f32x4*)out);
}

// Round 10
// 202.308 us; speedup vs baseline: 1.0937x; 1.0775x over previous
//
#include <hip/hip_runtime.h>

// Paged KV-cache scatter write (float32).
//   kv_pages: (4096, 16, 16, 128)  -> out (full copy + scatter)
//   new_k, new_v: (8192, 8, 128)
//   t_pages, t_slots: (8192,) int32
// Semantics: out[p,s,0::2,:] = new_k[i]; out[p,s,1::2,:] = new_v[i]
// with numpy last-write-wins on duplicate (p,s) and mode='drop' bounds.
//
// R10: single fused kernel (only replay-safe structure, R7 post-mortem).
// vs R9: BRANCHLESS streaming loop. The per-row `if (w<0)` branch blocked
// load hoisting across rows -> ~2 loads in flight per thread. Now the source
// address is a pointer cndmask (wave-uniform w, no divergence) and the row
// loop is unrolled 4x so the compiler can keep ~8 load/store pairs in its
// scheduling window with only ~4 values live (R5 showed 16-deep + pointer
// tables blows VGPR; this is the middle ground).
// Key geometry: a thread's two slots (t=tid, tid+256) hit SAME-parity heads,
// so the k/v select is thread-invariant; scatter offsets differ by 128.

#define NUM_PAGES 4096
#define PAGE_SIZE 16
#define KV_HEADS 8
#define HEAD_SIZE 128
#define N_TOKENS 8192
#define NUM_ROWS (NUM_PAGES * PAGE_SIZE)       // 65536 (page,slot) rows
#define ROW_F4 (2 * KV_HEADS * HEAD_SIZE / 4)  // 512 f32x4 per row (8 KiB)
#define ROWS_PER_BLOCK 32                      // grid 2048 = full residency
#define HEAD_F4 (HEAD_SIZE / 4)                // 32 f32x4 per head
#define TOK_F4 (KV_HEADS * HEAD_SIZE / 4)      // 256 f32x4 per token (k or v)

typedef float f32x4 __attribute__((ext_vector_type(4)));
typedef int   i32x4 __attribute__((ext_vector_type(4)));

__global__ __launch_bounds__(256)
void kv_fused_kernel(const f32x4* __restrict__ kv_pages,
                     const f32x4* __restrict__ new_k,
                     const f32x4* __restrict__ new_v,
                     const i32x4* __restrict__ t_pages4,
                     const i32x4* __restrict__ t_slots4,
                     f32x4* __restrict__ out) {
    __shared__ int wlds[ROWS_PER_BLOCK];
    const int row0 = blockIdx.x * ROWS_PER_BLOCK;
    const int tid  = threadIdx.x;

    if (tid < ROWS_PER_BLOCK) wlds[tid] = -1;
    __syncthreads();

    // Winner scan: all 8192 tokens, int4-vectorized. Token arrays are 64 KB
    // total — L2/L3-resident. ~4 atomic hits per block, cold path.
    #pragma unroll
    for (int i = tid; i < N_TOKENS / 4; i += 256) {
        i32x4 p4 = t_pages4[i];
        i32x4 s4 = t_slots4[i];
        #pragma unroll
        for (int c = 0; c < 4; ++c) {
            int p = p4[c], s = s4[c];
            // mode='drop': out-of-range indices are ignored
            if ((unsigned)p < (unsigned)NUM_PAGES && (unsigned)s < (unsigned)PAGE_SIZE) {
                int d = p * PAGE_SIZE + s - row0;
                if ((unsigned)d < (unsigned)ROWS_PER_BLOCK)
                    atomicMax(&wlds[d], i * 4 + c);   // last token index wins
            }
        }
    }
    __syncthreads();

    // Thread-invariant scatter geometry: both slots of this thread are in
    // same-parity heads (head and head+8), so the k/v choice is fixed.
    const int head0 = tid >> 5;                  // 0..7
    const int d4    = tid & 31;
    const f32x4* srcArr = (head0 & 1) ? new_v : new_k;
    const int sc_base = (head0 >> 1) * HEAD_F4 + d4;   // + w*TOK_F4 per row

    // Streaming pass: branchless source select, 4-row pipeline window.
    #pragma unroll 4
    for (int r = 0; r < ROWS_PER_BLOCK; ++r) {
        const int w = wlds[r];                    // block-uniform (broadcast)
        const size_t base4 = (size_t)(row0 + r) * ROW_F4;
        const bool copy = (w < 0);
        const f32x4* cp = kv_pages + base4 + tid;
        const f32x4* sc = srcArr + (size_t)(copy ? 0 : w) * TOK_F4 + sc_base;
        const f32x4* a0 = copy ? cp        : sc;
        const f32x4* a1 = copy ? cp + 256  : sc + 4 * HEAD_F4;
        f32x4 v0 = __builtin_nontemporal_load(a0);
        f32x4 v1 = __builtin_nontemporal_load(a1);
        __builtin_nontemporal_store(v0, &out[base4 + tid]);
        __builtin_nontemporal_store(v1, &out[base4 + tid + 256]);
    }
}

extern "C" void kernel_launch(void* const* d_in, const int* in_sizes, int n_in,
                              void* d_out, int out_size, void* d_ws, size_t ws_size,
                              hipStream_t stream) {
    const float* kv_pages = (const float*)d_in[0];
    const float* new_k    = (const float*)d_in[1];
    const float* new_v    = (const float*)d_in[2];
    const int*   t_pages  = (const int*)d_in[3];
    const int*   t_slots  = (const int*)d_in[4];
    float*       out      = (float*)d_out;

    kv_fused_kernel<<<NUM_ROWS / ROWS_PER_BLOCK, 256, 0, stream>>>(
        (const f32x4*)kv_pages, (const f32x4*)new_k, (const f32x4*)new_v,
        (const i32x4*)t_pages, (const i32x4*)t_slots, (f32x4*)out);
}

// Round 11
// 198.623 us; speedup vs baseline: 1.1140x; 1.0186x over previous
//
#include <hip/hip_runtime.h>

// Paged KV-cache scatter write (float32).
//   kv_pages: (4096, 16, 16, 128)  -> out (full copy + scatter)
//   new_k, new_v: (8192, 8, 128)
//   t_pages, t_slots: (8192,) int32
// Semantics: out[p,s,0::2,:] = new_k[i]; out[p,s,1::2,:] = new_v[i]
// with numpy last-write-wins on duplicate (p,s) and mode='drop' bounds.
//
// R11: single fused kernel (only replay-safe structure, R7 post-mortem).
// = R10 (branchless cndmask source select, thread-invariant k/v parity,
// 32 rows/block, grid 2048 = full residency, nt loads + nt stores) with ONE
// change: streaming unroll 4 -> 8 (16 load/store pairs in the scheduler
// window; ~90 VGPR, ~6 blocks/CU is still ample streaming TLP).

#define NUM_PAGES 4096
#define PAGE_SIZE 16
#define KV_HEADS 8
#define HEAD_SIZE 128
#define N_TOKENS 8192
#define NUM_ROWS (NUM_PAGES * PAGE_SIZE)       // 65536 (page,slot) rows
#define ROW_F4 (2 * KV_HEADS * HEAD_SIZE / 4)  // 512 f32x4 per row (8 KiB)
#define ROWS_PER_BLOCK 32                      // grid 2048 = full residency
#define HEAD_F4 (HEAD_SIZE / 4)                // 32 f32x4 per head
#define TOK_F4 (KV_HEADS * HEAD_SIZE / 4)      // 256 f32x4 per token (k or v)

typedef float f32x4 __attribute__((ext_vector_type(4)));
typedef int   i32x4 __attribute__((ext_vector_type(4)));

__global__ __launch_bounds__(256)
void kv_fused_kernel(const f32x4* __restrict__ kv_pages,
                     const f32x4* __restrict__ new_k,
                     const f32x4* __restrict__ new_v,
                     const i32x4* __restrict__ t_pages4,
                     const i32x4* __restrict__ t_slots4,
                     f32x4* __restrict__ out) {
    __shared__ int wlds[ROWS_PER_BLOCK];
    const int row0 = blockIdx.x * ROWS_PER_BLOCK;
    const int tid  = threadIdx.x;

    if (tid < ROWS_PER_BLOCK) wlds[tid] = -1;
    __syncthreads();

    // Winner scan: all 8192 tokens, int4-vectorized. Token arrays are 64 KB
    // total — L2/L3-resident. ~4 atomic hits per block, cold path.
    #pragma unroll
    for (int i = tid; i < N_TOKENS / 4; i += 256) {
        i32x4 p4 = t_pages4[i];
        i32x4 s4 = t_slots4[i];
        #pragma unroll
        for (int c = 0; c < 4; ++c) {
            int p = p4[c], s = s4[c];
            // mode='drop': out-of-range indices are ignored
            if ((unsigned)p < (unsigned)NUM_PAGES && (unsigned)s < (unsigned)PAGE_SIZE) {
                int d = p * PAGE_SIZE + s - row0;
                if ((unsigned)d < (unsigned)ROWS_PER_BLOCK)
                    atomicMax(&wlds[d], i * 4 + c);   // last token index wins
            }
        }
    }
    __syncthreads();

    // Thread-invariant scatter geometry: both slots of this thread are in
    // same-parity heads (head and head+8), so the k/v choice is fixed.
    const int head0 = tid >> 5;                  // 0..7
    const int d4    = tid & 31;
    const f32x4* srcArr = (head0 & 1) ? new_v : new_k;
    const int sc_base = (head0 >> 1) * HEAD_F4 + d4;   // + w*TOK_F4 per row

    // Streaming pass: branchless source select, 8-row pipeline window.
    #pragma unroll 8
    for (int r = 0; r < ROWS_PER_BLOCK; ++r) {
        const int w = wlds[r];                    // block-uniform (broadcast)
        const size_t base4 = (size_t)(row0 + r) * ROW_F4;
        const bool copy = (w < 0);
        const f32x4* cp = kv_pages + base4 + tid;
        const f32x4* sc = srcArr + (size_t)(copy ? 0 : w) * TOK_F4 + sc_base;
        const f32x4* a0 = copy ? cp        : sc;
        const f32x4* a1 = copy ? cp + 256  : sc + 4 * HEAD_F4;
        f32x4 v0 = __builtin_nontemporal_load(a0);
        f32x4 v1 = __builtin_nontemporal_load(a1);
        __builtin_nontemporal_store(v0, &out[base4 + tid]);
        __builtin_nontemporal_store(v1, &out[base4 + tid + 256]);
    }
}

extern "C" void kernel_launch(void* const* d_in, const int* in_sizes, int n_in,
                              void* d_out, int out_size, void* d_ws, size_t ws_size,
                              hipStream_t stream) {
    const float* kv_pages = (const float*)d_in[0];
    const float* new_k    = (const float*)d_in[1];
    const float* new_v    = (const float*)d_in[2];
    const int*   t_pages  = (const int*)d_in[3];
    const int*   t_slots  = (const int*)d_in[4];
    float*       out      = (float*)d_out;

    kv_fused_kernel<<<NUM_ROWS / ROWS_PER_BLOCK, 256, 0, stream>>>(
        (const f32x4*)kv_pages, (const f32x4*)new_k, (const f32x4*)new_v,
        (const i32x4*)t_pages, (const i32x4*)t_slots, (f32x4*)out);
}